// Round 14
// baseline (1207.442 us; speedup 1.0000x reference)
//
#include <hip/hip_runtime.h>
#include <hip/hip_bf16.h>

typedef __attribute__((ext_vector_type(8))) short short8;
typedef __attribute__((ext_vector_type(4))) float f32x4;
typedef unsigned short ushort;
typedef unsigned long long u64;
typedef unsigned int u32;

#define AL(p) __hip_atomic_load((p), __ATOMIC_RELAXED, __HIP_MEMORY_SCOPE_AGENT)
#define AS(p,v) __hip_atomic_store((p), (v), __ATOMIC_RELAXED, __HIP_MEMORY_SCOPE_AGENT)
#define ALQ(p) __hip_atomic_load((p), __ATOMIC_ACQUIRE, __HIP_MEMORY_SCOPE_AGENT)

__device__ inline ushort f2bf(float x) {
  __hip_bfloat16 h = __float2bfloat16(x);
  return *reinterpret_cast<ushort*>(&h);
}
__device__ inline float bfhi2f(u32 lo) {
  union { u32 u; float f; } c; c.u = lo & 0xFFFF0000u; return c.f;
}
__device__ inline float bflo2f(u32 lo) {
  union { u32 u; float f; } c; c.u = lo << 16; return c.f;
}
__device__ inline u32 pk2(float a, float b) {
  return (u32)f2bf(__expf(a)) | ((u32)f2bf(__expf(b)) << 16);
}

// ---------------- 3 residual MLPs + weight casts in one dispatch (blockIdx.y selects) ----
__global__ __launch_bounds__(256) void mlp3_kernel(
    const float* X0, const float* W10, const float* b10, const float* W20, const float* b20,
    const float* g0, const float* be0, float* of0, ushort* ob0,
    const float* X1, const float* W11, const float* b11, const float* W21, const float* b21,
    const float* g1, const float* be1, float* of1, ushort* ob1,
    const float* X2, const float* W12, const float* b12, const float* W22, const float* b22,
    const float* g2, const float* be2, float* of2, ushort* ob2,
    const float* ca_i, ushort* ca_o, int nc_a,
    const float* cb_i, ushort* cb_o, int nc_b)
{
  int y = blockIdx.y;
  if (y == 3) {
    int i = blockIdx.x * 256 + threadIdx.x;
    int st = 64 * 256;
    for (; i < nc_a + nc_b; i += st) {
      if (i < nc_a) ca_o[i] = f2bf(ca_i[i]);
      else          cb_o[i - nc_a] = f2bf(cb_i[i - nc_a]);
    }
    return;
  }
  const float *X, *W1, *b1, *W2, *b2, *g, *beta; float* of32; ushort* obf;
  if (y == 0)      { X=X0; W1=W10; b1=b10; W2=W20; b2=b20; g=g0; beta=be0; of32=of0; obf=ob0; }
  else if (y == 1) { X=X1; W1=W11; b1=b11; W2=W21; b2=b21; g=g1; beta=be1; of32=of1; obf=ob1; }
  else             { X=X2; W1=W12; b1=b12; W2=W22; b2=b22; g=g2; beta=be2; of32=of2; obf=ob2; }

  __shared__ float Xs[16 * 260];
  __shared__ float H1s[16 * 260];
  __shared__ float mu_s[16], rs_s[16];
  int tid = threadIdx.x;
  int r0 = blockIdx.x * 16;
  for (int q = 0; q < 16; ++q) Xs[q * 260 + tid] = X[(r0 + q) * 256 + tid];
  __syncthreads();
  int r = tid & 15, jg = tid >> 4;
  for (int jj = 0; jj < 16; ++jj) {
    int j = jg * 16 + jj;
    const float4* wrow = (const float4*)(W1 + j * 256);
    const float4* xrow = (const float4*)(Xs + r * 260);
    float acc = 0.f;
#pragma unroll 8
    for (int kq = 0; kq < 64; ++kq) {
      float4 w = wrow[kq], x = xrow[kq];
      acc += w.x * x.x + w.y * x.y + w.z * x.z + w.w * x.w;
    }
    acc += b1[j];
    H1s[r * 260 + j] = acc > 0.f ? acc : 0.f;
  }
  __syncthreads();
  for (int jj = 0; jj < 16; ++jj) {
    int j = jg * 16 + jj;
    const float4* wrow = (const float4*)(W2 + j * 256);
    const float4* hrow = (const float4*)(H1s + r * 260);
    float acc = 0.f;
#pragma unroll 8
    for (int kq = 0; kq < 64; ++kq) {
      float4 w = wrow[kq], x = hrow[kq];
      acc += w.x * x.x + w.y * x.y + w.z * x.z + w.w * x.w;
    }
    acc += b2[j];
    float v = (acc > 0.f ? acc : 0.f) + H1s[r * 260 + j];
    Xs[r * 260 + j] = v;
  }
  __syncthreads();
  if (tid < 16) {
    float s = 0.f, s2 = 0.f;
    for (int k = 0; k < 256; ++k) { float x = Xs[tid * 260 + k]; s += x; s2 += x * x; }
    float mu = s * (1.0f / 256.0f);
    float var = s2 * (1.0f / 256.0f) - mu * mu;
    mu_s[tid] = mu; rs_s[tid] = rsqrtf(var + 1e-5f);
  }
  __syncthreads();
  for (int q = 0; q < 16; ++q) {
    float x = (Xs[q * 260 + tid] - mu_s[q]) * rs_s[q] * g[tid] + beta[tid];
    if (of32) of32[(r0 + q) * 256 + tid] = x;
    if (obf)  obf[(r0 + q) * 256 + tid] = f2bf(x);
  }
}

// ---------------- start head (256-thread body; 4 states/thread) ----------------
__device__ void shead_body(const float* __restrict__ h, const float* __restrict__ Wo,
                           const float* __restrict__ bo, float* __restrict__ start)
{
  __shared__ float red[4];
  __shared__ float lse_s;
  int tid = threadIdx.x;
  float lg[4];
  float s = 0.f;
#pragma unroll
  for (int q = 0; q < 4; ++q) {
    int state = q * 256 + tid;
    const float4* wr = (const float4*)Wo;
    const float4* hr = (const float4*)(h + state * 256);
    float acc = 0.f;
    for (int kq = 0; kq < 64; ++kq) {
      float4 w = wr[kq], x = hr[kq];
      acc += w.x * x.x + w.y * x.y + w.z * x.z + w.w * x.w;
    }
    acc += bo[0];
    lg[q] = acc;
    s += __expf(acc);
  }
  for (int m = 1; m < 64; m <<= 1) s += __shfl_xor(s, m);
  if ((tid & 63) == 0) red[tid >> 6] = s;
  __syncthreads();
  if (tid == 0) lse_s = logf(red[0] + red[1] + red[2] + red[3]);
  __syncthreads();
  float lse = lse_s;
#pragma unroll
  for (int q = 0; q < 4; ++q) start[q * 256 + tid] = lg[q] - lse;
}

// ---------------- bf16 MFMA GEMM body, tile 64x32, K=256, D = A @ B^T ----------------
__device__ void gemm_body(const ushort* __restrict__ A, const ushort* __restrict__ Bw,
                          int mode, int Nvalid, int chunks,
                          const float* __restrict__ bias,
                          float* __restrict__ out, float* __restrict__ esum,
                          const int* __restrict__ text, int bx, int by)
{
  __shared__ ushort As[64 * 264];
  __shared__ ushort Bs[32 * 264];
  int tid = threadIdx.x;
  int m0 = bx * 64;
#pragma unroll
  for (int q = 0; q < 8; ++q) {
    int idx = q * 256 + tid;
    int row = idx >> 5, c8 = idx & 31;
    *(short8*)(As + row * 264 + c8 * 8) = *(const short8*)(A + (m0 + row) * 256 + c8 * 8);
  }
  int lane = tid & 63, wave = tid >> 6;
  int r16 = lane & 15, quad = lane >> 4;
  float sacc[4] = {0.f, 0.f, 0.f, 0.f};

  for (int c = 0; c < chunks; ++c) {
    int n0 = (by * chunks + c) * 32;
    if (c) __syncthreads();
#pragma unroll
    for (int q = 0; q < 4; ++q) {
      int idx = q * 256 + tid;
      int row = idx >> 5, c8 = idx & 31;
      int grow = n0 + row;
      short8 val = {0, 0, 0, 0, 0, 0, 0, 0};
      if (mode == 2) {
        int v = text[(grow & 15) * 256 + (grow >> 4)];
        val = *(const short8*)(Bw + v * 256 + c8 * 8);
      } else if (grow < Nvalid) {
        val = *(const short8*)(Bw + grow * 256 + c8 * 8);
      }
      *(short8*)(Bs + row * 264 + c8 * 8) = val;
    }
    __syncthreads();
    f32x4 acc0 = {0.f, 0.f, 0.f, 0.f}, acc1 = {0.f, 0.f, 0.f, 0.f};
#pragma unroll
    for (int kb = 0; kb < 8; ++kb) {
      short8 a  = *(const short8*)(As + (wave * 16 + r16) * 264 + kb * 32 + quad * 8);
      short8 b0 = *(const short8*)(Bs + r16 * 264 + kb * 32 + quad * 8);
      short8 b1 = *(const short8*)(Bs + (16 + r16) * 264 + kb * 32 + quad * 8);
      acc0 = __builtin_amdgcn_mfma_f32_16x16x32_bf16(a, b0, acc0, 0, 0, 0);
      acc1 = __builtin_amdgcn_mfma_f32_16x16x32_bf16(a, b1, acc1, 0, 0, 0);
    }
    if (mode == 0) {
#pragma unroll
      for (int rr = 0; rr < 4; ++rr) {
        int row = m0 + wave * 16 + quad * 4 + rr;
        int c0 = n0 + r16, c1 = n0 + 16 + r16;
        out[row * 1024 + c0] = acc0[rr] + bias[c0];
        out[row * 1024 + c1] = acc1[rr] + bias[c1];
      }
    } else if (mode == 1) {
#pragma unroll
      for (int rr = 0; rr < 4; ++rr) {
        int c0 = n0 + r16, c1 = n0 + 16 + r16;
        float p0 = (c0 < Nvalid) ? __expf(acc0[rr] + bias[c0]) : 0.f;
        float p1 = (c1 < Nvalid) ? __expf(acc1[rr] + bias[c1]) : 0.f;
        sacc[rr] += p0 + p1;
      }
    } else {
      int c0 = m0 + wave * 16 + quad * 4;
      int tb0 = n0 + r16, tb1 = n0 + 16 + r16;
      int v0 = text[(tb0 & 15) * 256 + (tb0 >> 4)];
      int v1 = text[(tb1 & 15) * 256 + (tb1 >> 4)];
      float l0 = logf(esum[c0]), l1 = logf(esum[c0 + 1]);
      float l2 = logf(esum[c0 + 2]), l3 = logf(esum[c0 + 3]);
      float4 o0, o1;
      o0.x = acc0[0] + bias[v0] - l0; o0.y = acc0[1] + bias[v0] - l1;
      o0.z = acc0[2] + bias[v0] - l2; o0.w = acc0[3] + bias[v0] - l3;
      o1.x = acc1[0] + bias[v1] - l0; o1.y = acc1[1] + bias[v1] - l1;
      o1.z = acc1[2] + bias[v1] - l2; o1.w = acc1[3] + bias[v1] - l3;
      *(float4*)(out + tb0 * 1024 + c0) = o0;
      *(float4*)(out + tb1 * 1024 + c0) = o1;
    }
  }
  if (mode == 1) {
#pragma unroll
    for (int rr = 0; rr < 4; ++rr) {
      float s = sacc[rr];
      s += __shfl_xor(s, 1); s += __shfl_xor(s, 2);
      s += __shfl_xor(s, 4); s += __shfl_xor(s, 8);
      if (r16 == 0) atomicAdd(esum + m0 + wave * 16 + quad * 4 + rr, s);
    }
  }
}

// ---------------- transition row body: log_softmax + scatter exp(T) in B-fragment order ----
__device__ void trans_body(const float* __restrict__ logits, ushort* __restrict__ texp_frag,
                           int i)
{
  __shared__ float red[4];
  __shared__ float lse_s;
  int tid = threadIdx.x;
  float x[4];
  float s = 0.f;
#pragma unroll
  for (int q = 0; q < 4; ++q) { x[q] = logits[i * 1024 + q * 256 + tid]; s += __expf(x[q]); }
  for (int m = 1; m < 64; m <<= 1) s += __shfl_xor(s, m);
  if ((tid & 63) == 0) red[tid >> 6] = s;
  __syncthreads();
  if (tid == 0) lse_s = logf(red[0] + red[1] + red[2] + red[3]);
  __syncthreads();
  float lse = lse_s;
  int kblk = i >> 5, quad = (i >> 3) & 3, idx = i & 7;
#pragma unroll
  for (int q = 0; q < 4; ++q) {
    int j = q * 256 + tid;
    int pos = (((j >> 4) * 32 + kblk) * 64 + quad * 16 + (j & 15)) * 8 + idx;
    texp_frag[pos] = f2bf(__expf(x[q] - lse));
  }
}

// ---------------- fused: gemm0 (512) + gemm1 (640) + shead (1) ----------------
__global__ __launch_bounds__(256) void g01s_kernel(
    const ushort* At, const ushort* Bt, const float* t_bo, float* tlogits,
    const ushort* Ae, const ushort* Be, const float* e_bo, float* esum,
    const float* h_s, const float* s_Wo, const float* s_bo, float* start_v)
{
  int p = blockIdx.x;
  if (p < 512) {
    gemm_body(At, Bt, 0, 1024, 1, t_bo, tlogits, nullptr, nullptr, p & 15, p >> 4);
  } else if (p < 1152) {
    int q = p - 512;
    gemm_body(Ae, Be, 1, 10000, 8, e_bo, nullptr, esum, nullptr, q & 15, q >> 4);
  } else {
    shead_body(h_s, s_Wo, s_bo, start_v);
  }
}

// ---------------- merged: scan (64) + trans (1024) + gemm2 (2048) ----------------
// Producers wait on NOTHING (inputs complete at launch) and terminate -> deadlock-free
// regardless of dispatch order (only the 64 scan blocks spin; >=192 CUs stay free).
// Cross-XCD visibility: producer blocks __syncthreads (drains per-wave vmcnt) then
// thread0 RELEASE fetch_add on a counter (L2 writeback to L3); scan ACQUIRE-loads the
// counter before consuming (L2 invalidate; harmless - exchange atomics bypass L2 and
// texp/emitg rows are read-once). In steady state producers run ~55us while the scan
// consumes emitg row-group t*16 only at ~25+2.4t us -> zero stalls after warm-up.
// Scan body itself: R11/R9 proven floor structure verbatim (AGPR-T via asm MFMA "a"
// operands, exp/log exchange, full-set s_sleep(1) poll, 4 MFMA chains, 1 barrier/step).
__global__ __launch_bounds__(256, 1) void tgscan_kernel(
    const float* __restrict__ tlogits, ushort* __restrict__ texp_frag,
    const ushort* __restrict__ Ae, const ushort* __restrict__ Be,
    const float* __restrict__ e_bo, float* __restrict__ emitg,
    float* __restrict__ esum, const int* __restrict__ text,
    const float* __restrict__ start_v,
    u64* __restrict__ abuf,            // [2 parity][4 group][2048]
    float* __restrict__ out,
    u32* __restrict__ cnt)             // [0]=trans done, [1+by]=gemm2 by-group done
{
  int p = blockIdx.x;
  if (p >= 64) {
    if (p < 1088) {
      trans_body(tlogits, texp_frag, p - 64);
      __syncthreads();
      if (threadIdx.x == 0)
        __hip_atomic_fetch_add(cnt, 1u, __ATOMIC_RELEASE, __HIP_MEMORY_SCOPE_AGENT);
    } else {
      int q = p - 1088;
      gemm_body(Ae, Be, 2, 4096, 1, e_bo, emitg, esum, text, q & 15, q >> 4);
      __syncthreads();
      if (threadIdx.x == 0)
        __hip_atomic_fetch_add(cnt + 1 + (q >> 4), 1u, __ATOMIC_RELEASE, __HIP_MEMORY_SCOPE_AGENT);
    }
    return;
  }

  __shared__ __align__(16) char Asb[2][4 * 2080];  // 16.3 KB: [parity][row*2080 + 2*col]
  __shared__ float redw[4][4], reds[4][4];

  int tid = threadIdx.x, lane = tid & 63, wave = tid >> 6;
  int r16 = lane & 15, quad = lane >> 4;
  int bg = p & 3, cb = p >> 2;
  int b0 = bg * 4;                      // global batches b0..b0+3

  // wait: texp_frag fully written (all 1024 trans blocks released)
  while (ALQ(cnt) < 1024u) __builtin_amdgcn_s_sleep(8);

  // one-time load of this wave's T tile; pin into AGPRs
  const short8* tg = (const short8*)texp_frag + (size_t)cb * 8192 + wave * 2048;
  short8 treg[32];
#pragma unroll
  for (int k = 0; k < 32; ++k) treg[k] = tg[k * 64 + lane];
#pragma unroll
  for (int k = 0; k < 32; ++k) asm volatile("" : "+a"(treg[k]));

  int colw = cb * 64 + wave * 16 + r16;           // this lane's output col
  int abase = (r16 & 3) * 2080 + quad * 16;       // A-frag byte offset (garbage rows ok)

  // wait: emitg rows 0..31 (by-group 0) ready for seed + t=1 prefetch
  while (ALQ(cnt + 1) < 16u) __builtin_amdgcn_s_sleep(8);

  float m_r[4], Bs[4];
  // ---- seed: A(0) = exp(alpha0 - alpha0[col0]), offset = alpha0[col0] ----
#pragma unroll
  for (int i = 0; i < 4; ++i) {
    m_r[i] = start_v[0] + emitg[(size_t)(b0 + i) * 1024];
    Bs[i] = m_r[i];
  }
  {
    int c0 = 2 * tid, c2 = 2 * tid + 512;
    char* ab = Asb[1];
#pragma unroll
    for (int r = 0; r < 4; ++r) {
      const float* eb = emitg + (size_t)(b0 + r) * 1024;
      float v0 = start_v[c0] + eb[c0],     v1 = start_v[c0 + 1] + eb[c0 + 1];
      float v2 = start_v[c2] + eb[c2],     v3 = start_v[c2 + 1] + eb[c2 + 1];
      *(u32*)(ab + r * 2080 + 4 * tid)        = pk2(v0 - m_r[r], v1 - m_r[r]);
      *(u32*)(ab + r * 2080 + 1024 + 4 * tid) = pk2(v2 - m_r[r], v3 - m_r[r]);
    }
  }
  __syncthreads();   // t=1 pack ready

  for (int t = 1; t < 256; ++t) {
    // emitg readiness: by-group t/2 (changes at even t; t=1 covered by seed wait)
    if ((t & 1) == 0) {
      const u32* ct = cnt + 1 + (t >> 1);
      while (ALQ(ct) < 16u) __builtin_amdgcn_s_sleep(2);
    }
    // emission prefetch (off critical chain; consumed after K-loop)
    float e0 = 0.f, e1 = 0.f, e2 = 0.f, e3 = 0.f;
    if (quad == 0) {
      const float* ep = emitg + (size_t)(t * 16 + b0) * 1024 + colw;
      e0 = ep[0]; e1 = ep[1024]; e2 = ep[2048]; e3 = ep[3072];
    }

    // K-loop: B from AGPRs (asm), A broadcast-read from LDS; 4 independent chains
    const char* ab = Asb[t & 1];
    f32x4 a0, a1, a2, a3;
    {
      short8 f0 = *(const short8*)(ab + abase);
      short8 f1 = *(const short8*)(ab + abase + 64);
      short8 f2 = *(const short8*)(ab + abase + 128);
      short8 f3 = *(const short8*)(ab + abase + 192);
      asm volatile("v_mfma_f32_16x16x32_bf16 %0, %1, %2, 0" : "=v"(a0) : "v"(f0), "a"(treg[0]));
      asm volatile("v_mfma_f32_16x16x32_bf16 %0, %1, %2, 0" : "=v"(a1) : "v"(f1), "a"(treg[1]));
      asm volatile("v_mfma_f32_16x16x32_bf16 %0, %1, %2, 0" : "=v"(a2) : "v"(f2), "a"(treg[2]));
      asm volatile("v_mfma_f32_16x16x32_bf16 %0, %1, %2, 0" : "=v"(a3) : "v"(f3), "a"(treg[3]));
    }
#pragma unroll
    for (int kb = 4; kb < 32; kb += 4) {
      short8 f0 = *(const short8*)(ab + abase + kb * 64);
      short8 f1 = *(const short8*)(ab + abase + kb * 64 + 64);
      short8 f2 = *(const short8*)(ab + abase + kb * 64 + 128);
      short8 f3 = *(const short8*)(ab + abase + kb * 64 + 192);
      asm volatile("v_mfma_f32_16x16x32_bf16 %0, %1, %2, %0" : "+v"(a0) : "v"(f0), "a"(treg[kb + 0]));
      asm volatile("v_mfma_f32_16x16x32_bf16 %0, %1, %2, %0" : "+v"(a1) : "v"(f1), "a"(treg[kb + 1]));
      asm volatile("v_mfma_f32_16x16x32_bf16 %0, %1, %2, %0" : "+v"(a2) : "v"(f2), "a"(treg[kb + 2]));
      asm volatile("v_mfma_f32_16x16x32_bf16 %0, %1, %2, %0" : "+v"(a3) : "v"(f3), "a"(treg[kb + 3]));
    }
    asm volatile("s_nop 7\n\ts_nop 7\n\ts_nop 1"
                 : "+v"(a0), "+v"(a1), "+v"(a2), "+v"(a3));
    f32x4 acc = (a0 + a1) + (a2 + a3);

    // epilogue: quad0 lanes hold batches b0..b0+3 (rows 0-3) for col colw
    if (quad == 0) {
      float d0 = __logf(acc[0]) + e0;
      float d1 = __logf(acc[1]) + e1;
      float d2 = __logf(acc[2]) + e2;
      float d3 = __logf(acc[3]) + e3;
      u64 tag = ((u64)(u32)t) << 32;
      u64* ob = abuf + (t & 1) * 8192 + bg * 2048 + colw;
      AS(ob,        tag | (u64)((u32)f2bf(d0) | ((u32)f2bf(d1) << 16)));
      AS(ob + 1024, tag | (u64)((u32)f2bf(d2) | ((u32)f2bf(d3) << 16)));
    }

    if (t < 255) {
      // poll tag t: 8 data words (4 cols x 2 batch-pairs) + 2 normalizer (col-0) words
      u64 x0, x1, x2, x3, x4, x5, x6, x7, n0, n1;
      {
        const u64* buf = abuf + (t & 1) * 8192 + bg * 2048;
        int oa = 2 * tid, oc = 2 * tid + 512;
        u32 want = (u32)t;
        bool first = true;
        for (;;) {
          if (!first) __builtin_amdgcn_s_sleep(1);
          first = false;
          x0 = AL(buf + oa);        x1 = AL(buf + oa + 1);
          x2 = AL(buf + oc);        x3 = AL(buf + oc + 1);
          x4 = AL(buf + 1024 + oa); x5 = AL(buf + 1024 + oa + 1);
          x6 = AL(buf + 1024 + oc); x7 = AL(buf + 1024 + oc + 1);
          n0 = AL(buf);             n1 = AL(buf + 1024);
          u32 bad = ((u32)(x0 >> 32) ^ want) | ((u32)(x1 >> 32) ^ want) |
                    ((u32)(x2 >> 32) ^ want) | ((u32)(x3 >> 32) ^ want) |
                    ((u32)(x4 >> 32) ^ want) | ((u32)(x5 >> 32) ^ want) |
                    ((u32)(x6 >> 32) ^ want) | ((u32)(x7 >> 32) ^ want) |
                    ((u32)(n0 >> 32) ^ want) | ((u32)(n1 >> 32) ^ want);
          if (bad == 0) break;
        }
      }
      m_r[0] = bflo2f((u32)n0); m_r[1] = bfhi2f((u32)n0);
      m_r[2] = bflo2f((u32)n1); m_r[3] = bfhi2f((u32)n1);
      Bs[0] += m_r[0]; Bs[1] += m_r[1]; Bs[2] += m_r[2]; Bs[3] += m_r[3];

      // pack A(t+1): row r <- batch b0+r; lo/hi select within batch-pair words
      char* aw = Asb[(t + 1) & 1];
      u32 l0 = (u32)x0, l1 = (u32)x1, l2 = (u32)x2, l3 = (u32)x3;
      u32 l4 = (u32)x4, l5 = (u32)x5, l6 = (u32)x6, l7 = (u32)x7;
      *(u32*)(aw + 4 * tid)                = pk2(bflo2f(l0) - m_r[0], bflo2f(l1) - m_r[0]);
      *(u32*)(aw + 1024 + 4 * tid)         = pk2(bflo2f(l2) - m_r[0], bflo2f(l3) - m_r[0]);
      *(u32*)(aw + 2080 + 4 * tid)         = pk2(bfhi2f(l0) - m_r[1], bfhi2f(l1) - m_r[1]);
      *(u32*)(aw + 2080 + 1024 + 4 * tid)  = pk2(bfhi2f(l2) - m_r[1], bfhi2f(l3) - m_r[1]);
      *(u32*)(aw + 4160 + 4 * tid)         = pk2(bflo2f(l4) - m_r[2], bflo2f(l5) - m_r[2]);
      *(u32*)(aw + 4160 + 1024 + 4 * tid)  = pk2(bflo2f(l6) - m_r[2], bflo2f(l7) - m_r[2]);
      *(u32*)(aw + 6240 + 4 * tid)         = pk2(bfhi2f(l4) - m_r[3], bfhi2f(l5) - m_r[3]);
      *(u32*)(aw + 6240 + 1024 + 4 * tid)  = pk2(bfhi2f(l6) - m_r[3], bfhi2f(l7) - m_r[3]);
      __syncthreads();   // A(t+1) ready (only barrier per step)
    }
  }

  // ---- group leader (cb==0): reduce final delta + Bs -> atomicAdd(out) ----
  if (cb == 0) {
    const u64* fb = abuf + 8192 + bg * 2048;   // parity of t=255
    int oa = 2 * tid, oc = 2 * tid + 512;
    u64 x0, x1, x2, x3, x4, x5, x6, x7;
    {
      bool first = true;
      for (;;) {
        if (!first) __builtin_amdgcn_s_sleep(1);
        first = false;
        x0 = AL(fb + oa);        x1 = AL(fb + oa + 1);
        x2 = AL(fb + oc);        x3 = AL(fb + oc + 1);
        x4 = AL(fb + 1024 + oa); x5 = AL(fb + 1024 + oa + 1);
        x6 = AL(fb + 1024 + oc); x7 = AL(fb + 1024 + oc + 1);
        u32 bad = ((u32)(x0 >> 32) ^ 255u) | ((u32)(x1 >> 32) ^ 255u) |
                  ((u32)(x2 >> 32) ^ 255u) | ((u32)(x3 >> 32) ^ 255u) |
                  ((u32)(x4 >> 32) ^ 255u) | ((u32)(x5 >> 32) ^ 255u) |
                  ((u32)(x6 >> 32) ^ 255u) | ((u32)(x7 >> 32) ^ 255u);
        if (bad == 0) break;
      }
    }
    float bv[4][4];
    bv[0][0] = bflo2f((u32)x0); bv[0][1] = bflo2f((u32)x1); bv[0][2] = bflo2f((u32)x2); bv[0][3] = bflo2f((u32)x3);
    bv[1][0] = bfhi2f((u32)x0); bv[1][1] = bfhi2f((u32)x1); bv[1][2] = bfhi2f((u32)x2); bv[1][3] = bfhi2f((u32)x3);
    bv[2][0] = bflo2f((u32)x4); bv[2][1] = bflo2f((u32)x5); bv[2][2] = bflo2f((u32)x6); bv[2][3] = bflo2f((u32)x7);
    bv[3][0] = bfhi2f((u32)x4); bv[3][1] = bfhi2f((u32)x5); bv[3][2] = bfhi2f((u32)x6); bv[3][3] = bfhi2f((u32)x7);
    float M[4], S[4];
#pragma unroll
    for (int i = 0; i < 4; ++i)
      M[i] = fmaxf(fmaxf(bv[i][0], bv[i][1]), fmaxf(bv[i][2], bv[i][3]));
    for (int off = 1; off < 64; off <<= 1) {
#pragma unroll
      for (int i = 0; i < 4; ++i) M[i] = fmaxf(M[i], __shfl_xor(M[i], off));
    }
    if (lane == 0) { redw[wave][0]=M[0]; redw[wave][1]=M[1]; redw[wave][2]=M[2]; redw[wave][3]=M[3]; }
    __syncthreads();
#pragma unroll
    for (int i = 0; i < 4; ++i)
      M[i] = fmaxf(fmaxf(redw[0][i], redw[1][i]), fmaxf(redw[2][i], redw[3][i]));
#pragma unroll
    for (int i = 0; i < 4; ++i)
      S[i] = __expf(bv[i][0] - M[i]) + __expf(bv[i][1] - M[i]) +
             __expf(bv[i][2] - M[i]) + __expf(bv[i][3] - M[i]);
    for (int off = 1; off < 64; off <<= 1) {
#pragma unroll
      for (int i = 0; i < 4; ++i) S[i] += __shfl_xor(S[i], off);
    }
    if (lane == 0) { reds[wave][0]=S[0]; reds[wave][1]=S[1]; reds[wave][2]=S[2]; reds[wave][3]=S[3]; }
    __syncthreads();
    if (tid == 0) {
      float tot = 0.f;
#pragma unroll
      for (int i = 0; i < 4; ++i) {
        float Sg = reds[0][i] + reds[1][i] + reds[2][i] + reds[3][i];
        tot += Bs[i] + M[i] + logf(Sg);
      }
      atomicAdd(out, tot);
    }
  }
}

extern "C" void kernel_launch(void* const* d_in, const int* in_sizes, int n_in,
                              void* d_out, int out_size, void* d_ws, size_t ws_size,
                              hipStream_t stream)
{
  (void)in_sizes; (void)n_in; (void)out_size; (void)ws_size;
  const float* start_emb = (const float*)d_in[0];
  const float* state_emb = (const float*)d_in[1];
  const float* pre_emb   = (const float*)d_in[2];
  const float* s_W1 = (const float*)d_in[3];  const float* s_b1 = (const float*)d_in[4];
  const float* s_W2 = (const float*)d_in[5];  const float* s_b2 = (const float*)d_in[6];
  const float* s_g  = (const float*)d_in[7];  const float* s_be = (const float*)d_in[8];
  const float* s_Wo = (const float*)d_in[9];  const float* s_bo = (const float*)d_in[10];
  const float* t_W1 = (const float*)d_in[11]; const float* t_b1 = (const float*)d_in[12];
  const float* t_W2 = (const float*)d_in[13]; const float* t_b2 = (const float*)d_in[14];
  const float* t_g  = (const float*)d_in[15]; const float* t_be = (const float*)d_in[16];
  const float* t_Wo = (const float*)d_in[17]; const float* t_bo = (const float*)d_in[18];
  const float* e_W1 = (const float*)d_in[19]; const float* e_b1 = (const float*)d_in[20];
  const float* e_W2 = (const float*)d_in[21]; const float* e_b2 = (const float*)d_in[22];
  const float* e_g  = (const float*)d_in[23]; const float* e_be = (const float*)d_in[24];
  const float* e_Wo = (const float*)d_in[25]; const float* e_bo = (const float*)d_in[26];
  const int*   text = (const int*)d_in[27];
  float* out = (float*)d_out;

  char* ws = (char*)d_ws;
  size_t off = 0;
  auto alloc = [&](size_t bytes) -> char* {
    char* p = ws + off;
    off = (off + bytes + 255) & ~(size_t)255;
    return p;
  };
  float* esum       = (float*)alloc(1024 * 4);     // @0 (memset)
  u64*   abuf       = (u64*)alloc(2 * 8192 * 8);   // 128KB tagged exchange (memset)
  u32*   cnt        = (u32*)alloc(256 * 4);        // [0]=trans, [1..128]=gemm2 by (memset)
  float* start_v    = (float*)alloc(1024 * 4);
  float* h_s        = (float*)alloc(1024 * 256 * 4);
  ushort* h_t_bf    = (ushort*)alloc(1024 * 256 * 2);
  ushort* h_e_bf    = (ushort*)alloc(1024 * 256 * 2);
  ushort* tWo_bf    = (ushort*)alloc(1024 * 256 * 2);
  ushort* eWo_bf    = (ushort*)alloc(10000 * 256 * 2);
  float* tlogits    = (float*)alloc(1024 * 1024 * 4);
  ushort* texp_frag = (ushort*)alloc(1024 * 1024 * 2);
  float* emitg      = (float*)alloc(4096 * 1024 * 4);

  hipMemsetAsync(ws, 0, 4096 + 2 * 8192 * 8 + 1024, stream);  // esum + abuf + cnt
  hipMemsetAsync(d_out, 0, 4, stream);                        // leaders atomicAdd into out

  mlp3_kernel<<<dim3(64, 4), 256, 0, stream>>>(
      start_emb, s_W1, s_b1, s_W2, s_b2, s_g, s_be, h_s, nullptr,
      state_emb, t_W1, t_b1, t_W2, t_b2, t_g, t_be, nullptr, h_t_bf,
      pre_emb,  e_W1, e_b1, e_W2, e_b2, e_g, e_be, nullptr, h_e_bf,
      t_Wo, tWo_bf, 1024 * 256, e_Wo, eWo_bf, 10000 * 256);

  g01s_kernel<<<1153, 256, 0, stream>>>(
      h_t_bf, tWo_bf, t_bo, tlogits,
      h_e_bf, eWo_bf, e_bo, esum,
      h_s, s_Wo, s_bo, start_v);

  tgscan_kernel<<<3136, 256, 0, stream>>>(
      tlogits, texp_frag,
      h_e_bf, eWo_bf, e_bo, emitg,
      esum, text, start_v, abuf, out, cnt);
}

// Round 15
// 871.530 us; speedup vs baseline: 1.3854x; 1.3854x over previous
//
#include <hip/hip_runtime.h>
#include <hip/hip_bf16.h>

typedef __attribute__((ext_vector_type(8))) short short8;
typedef __attribute__((ext_vector_type(4))) float f32x4;
typedef unsigned short ushort;
typedef unsigned long long u64;
typedef unsigned int u32;

#define AL(p) __hip_atomic_load((p), __ATOMIC_RELAXED, __HIP_MEMORY_SCOPE_AGENT)
#define AS(p,v) __hip_atomic_store((p), (v), __ATOMIC_RELAXED, __HIP_MEMORY_SCOPE_AGENT)

__device__ inline ushort f2bf(float x) {
  __hip_bfloat16 h = __float2bfloat16(x);
  return *reinterpret_cast<ushort*>(&h);
}
__device__ inline float bfhi2f(u32 lo) {
  union { u32 u; float f; } c; c.u = lo & 0xFFFF0000u; return c.f;
}
__device__ inline float bflo2f(u32 lo) {
  union { u32 u; float f; } c; c.u = lo << 16; return c.f;
}
__device__ inline u32 pk2(float a, float b) {
  return (u32)f2bf(__expf(a)) | ((u32)f2bf(__expf(b)) << 16);
}

// ---------------- 3 residual MLPs + weight casts in one dispatch (blockIdx.y selects) ----
__global__ __launch_bounds__(256) void mlp3_kernel(
    const float* X0, const float* W10, const float* b10, const float* W20, const float* b20,
    const float* g0, const float* be0, float* of0, ushort* ob0,
    const float* X1, const float* W11, const float* b11, const float* W21, const float* b21,
    const float* g1, const float* be1, float* of1, ushort* ob1,
    const float* X2, const float* W12, const float* b12, const float* W22, const float* b22,
    const float* g2, const float* be2, float* of2, ushort* ob2,
    const float* ca_i, ushort* ca_o, int nc_a,
    const float* cb_i, ushort* cb_o, int nc_b)
{
  int y = blockIdx.y;
  if (y == 3) {
    int i = blockIdx.x * 256 + threadIdx.x;
    int st = 64 * 256;
    for (; i < nc_a + nc_b; i += st) {
      if (i < nc_a) ca_o[i] = f2bf(ca_i[i]);
      else          cb_o[i - nc_a] = f2bf(cb_i[i - nc_a]);
    }
    return;
  }
  const float *X, *W1, *b1, *W2, *b2, *g, *beta; float* of32; ushort* obf;
  if (y == 0)      { X=X0; W1=W10; b1=b10; W2=W20; b2=b20; g=g0; beta=be0; of32=of0; obf=ob0; }
  else if (y == 1) { X=X1; W1=W11; b1=b11; W2=W21; b2=b21; g=g1; beta=be1; of32=of1; obf=ob1; }
  else             { X=X2; W1=W12; b1=b12; W2=W22; b2=b22; g=g2; beta=be2; of32=of2; obf=ob2; }

  __shared__ float Xs[16 * 260];
  __shared__ float H1s[16 * 260];
  __shared__ float mu_s[16], rs_s[16];
  int tid = threadIdx.x;
  int r0 = blockIdx.x * 16;
  for (int q = 0; q < 16; ++q) Xs[q * 260 + tid] = X[(r0 + q) * 256 + tid];
  __syncthreads();
  int r = tid & 15, jg = tid >> 4;
  for (int jj = 0; jj < 16; ++jj) {
    int j = jg * 16 + jj;
    const float4* wrow = (const float4*)(W1 + j * 256);
    const float4* xrow = (const float4*)(Xs + r * 260);
    float acc = 0.f;
#pragma unroll 8
    for (int kq = 0; kq < 64; ++kq) {
      float4 w = wrow[kq], x = xrow[kq];
      acc += w.x * x.x + w.y * x.y + w.z * x.z + w.w * x.w;
    }
    acc += b1[j];
    H1s[r * 260 + j] = acc > 0.f ? acc : 0.f;
  }
  __syncthreads();
  for (int jj = 0; jj < 16; ++jj) {
    int j = jg * 16 + jj;
    const float4* wrow = (const float4*)(W2 + j * 256);
    const float4* hrow = (const float4*)(H1s + r * 260);
    float acc = 0.f;
#pragma unroll 8
    for (int kq = 0; kq < 64; ++kq) {
      float4 w = wrow[kq], x = hrow[kq];
      acc += w.x * x.x + w.y * x.y + w.z * x.z + w.w * x.w;
    }
    acc += b2[j];
    float v = (acc > 0.f ? acc : 0.f) + H1s[r * 260 + j];
    Xs[r * 260 + j] = v;
  }
  __syncthreads();
  if (tid < 16) {
    float s = 0.f, s2 = 0.f;
    for (int k = 0; k < 256; ++k) { float x = Xs[tid * 260 + k]; s += x; s2 += x * x; }
    float mu = s * (1.0f / 256.0f);
    float var = s2 * (1.0f / 256.0f) - mu * mu;
    mu_s[tid] = mu; rs_s[tid] = rsqrtf(var + 1e-5f);
  }
  __syncthreads();
  for (int q = 0; q < 16; ++q) {
    float x = (Xs[q * 260 + tid] - mu_s[q]) * rs_s[q] * g[tid] + beta[tid];
    if (of32) of32[(r0 + q) * 256 + tid] = x;
    if (obf)  obf[(r0 + q) * 256 + tid] = f2bf(x);
  }
}

// ---------------- start head (256-thread body; 4 states/thread) ----------------
__device__ void shead_body(const float* __restrict__ h, const float* __restrict__ Wo,
                           const float* __restrict__ bo, float* __restrict__ start)
{
  __shared__ float red[4];
  __shared__ float lse_s;
  int tid = threadIdx.x;
  float lg[4];
  float s = 0.f;
#pragma unroll
  for (int q = 0; q < 4; ++q) {
    int state = q * 256 + tid;
    const float4* wr = (const float4*)Wo;
    const float4* hr = (const float4*)(h + state * 256);
    float acc = 0.f;
    for (int kq = 0; kq < 64; ++kq) {
      float4 w = wr[kq], x = hr[kq];
      acc += w.x * x.x + w.y * x.y + w.z * x.z + w.w * x.w;
    }
    acc += bo[0];
    lg[q] = acc;
    s += __expf(acc);
  }
  for (int m = 1; m < 64; m <<= 1) s += __shfl_xor(s, m);
  if ((tid & 63) == 0) red[tid >> 6] = s;
  __syncthreads();
  if (tid == 0) lse_s = logf(red[0] + red[1] + red[2] + red[3]);
  __syncthreads();
  float lse = lse_s;
#pragma unroll
  for (int q = 0; q < 4; ++q) start[q * 256 + tid] = lg[q] - lse;
}

// ---------------- bf16 MFMA GEMM body, tile 64x32, K=256, D = A @ B^T ----------------
__device__ void gemm_body(const ushort* __restrict__ A, const ushort* __restrict__ Bw,
                          int mode, int Nvalid, int chunks,
                          const float* __restrict__ bias,
                          float* __restrict__ out, float* __restrict__ esum,
                          const int* __restrict__ text, int bx, int by)
{
  __shared__ ushort As[64 * 264];
  __shared__ ushort Bs[32 * 264];
  int tid = threadIdx.x;
  int m0 = bx * 64;
#pragma unroll
  for (int q = 0; q < 8; ++q) {
    int idx = q * 256 + tid;
    int row = idx >> 5, c8 = idx & 31;
    *(short8*)(As + row * 264 + c8 * 8) = *(const short8*)(A + (m0 + row) * 256 + c8 * 8);
  }
  int lane = tid & 63, wave = tid >> 6;
  int r16 = lane & 15, quad = lane >> 4;
  float sacc[4] = {0.f, 0.f, 0.f, 0.f};

  for (int c = 0; c < chunks; ++c) {
    int n0 = (by * chunks + c) * 32;
    if (c) __syncthreads();
#pragma unroll
    for (int q = 0; q < 4; ++q) {
      int idx = q * 256 + tid;
      int row = idx >> 5, c8 = idx & 31;
      int grow = n0 + row;
      short8 val = {0, 0, 0, 0, 0, 0, 0, 0};
      if (mode == 2) {
        int v = text[(grow & 15) * 256 + (grow >> 4)];
        val = *(const short8*)(Bw + v * 256 + c8 * 8);
      } else if (grow < Nvalid) {
        val = *(const short8*)(Bw + grow * 256 + c8 * 8);
      }
      *(short8*)(Bs + row * 264 + c8 * 8) = val;
    }
    __syncthreads();
    f32x4 acc0 = {0.f, 0.f, 0.f, 0.f}, acc1 = {0.f, 0.f, 0.f, 0.f};
#pragma unroll
    for (int kb = 0; kb < 8; ++kb) {
      short8 a  = *(const short8*)(As + (wave * 16 + r16) * 264 + kb * 32 + quad * 8);
      short8 b0 = *(const short8*)(Bs + r16 * 264 + kb * 32 + quad * 8);
      short8 b1 = *(const short8*)(Bs + (16 + r16) * 264 + kb * 32 + quad * 8);
      acc0 = __builtin_amdgcn_mfma_f32_16x16x32_bf16(a, b0, acc0, 0, 0, 0);
      acc1 = __builtin_amdgcn_mfma_f32_16x16x32_bf16(a, b1, acc1, 0, 0, 0);
    }
    if (mode == 0) {
#pragma unroll
      for (int rr = 0; rr < 4; ++rr) {
        int row = m0 + wave * 16 + quad * 4 + rr;
        int c0 = n0 + r16, c1 = n0 + 16 + r16;
        out[row * 1024 + c0] = acc0[rr] + bias[c0];
        out[row * 1024 + c1] = acc1[rr] + bias[c1];
      }
    } else if (mode == 1) {
#pragma unroll
      for (int rr = 0; rr < 4; ++rr) {
        int c0 = n0 + r16, c1 = n0 + 16 + r16;
        float p0 = (c0 < Nvalid) ? __expf(acc0[rr] + bias[c0]) : 0.f;
        float p1 = (c1 < Nvalid) ? __expf(acc1[rr] + bias[c1]) : 0.f;
        sacc[rr] += p0 + p1;
      }
    } else {
      int c0 = m0 + wave * 16 + quad * 4;
      int tb0 = n0 + r16, tb1 = n0 + 16 + r16;
      int v0 = text[(tb0 & 15) * 256 + (tb0 >> 4)];
      int v1 = text[(tb1 & 15) * 256 + (tb1 >> 4)];
      float l0 = logf(esum[c0]), l1 = logf(esum[c0 + 1]);
      float l2 = logf(esum[c0 + 2]), l3 = logf(esum[c0 + 3]);
      float4 o0, o1;
      o0.x = acc0[0] + bias[v0] - l0; o0.y = acc0[1] + bias[v0] - l1;
      o0.z = acc0[2] + bias[v0] - l2; o0.w = acc0[3] + bias[v0] - l3;
      o1.x = acc1[0] + bias[v1] - l0; o1.y = acc1[1] + bias[v1] - l1;
      o1.z = acc1[2] + bias[v1] - l2; o1.w = acc1[3] + bias[v1] - l3;
      *(float4*)(out + tb0 * 1024 + c0) = o0;
      *(float4*)(out + tb1 * 1024 + c0) = o1;
    }
  }
  if (mode == 1) {
#pragma unroll
    for (int rr = 0; rr < 4; ++rr) {
      float s = sacc[rr];
      s += __shfl_xor(s, 1); s += __shfl_xor(s, 2);
      s += __shfl_xor(s, 4); s += __shfl_xor(s, 8);
      if (r16 == 0) atomicAdd(esum + m0 + wave * 16 + quad * 4 + rr, s);
    }
  }
}

// ---------------- transition row body: log_softmax + scatter exp(T) in B-fragment order ----
__device__ void trans_body(const float* __restrict__ logits, ushort* __restrict__ texp_frag,
                           int i)
{
  __shared__ float red[4];
  __shared__ float lse_s;
  int tid = threadIdx.x;
  float x[4];
  float s = 0.f;
#pragma unroll
  for (int q = 0; q < 4; ++q) { x[q] = logits[i * 1024 + q * 256 + tid]; s += __expf(x[q]); }
  for (int m = 1; m < 64; m <<= 1) s += __shfl_xor(s, m);
  if ((tid & 63) == 0) red[tid >> 6] = s;
  __syncthreads();
  if (tid == 0) lse_s = logf(red[0] + red[1] + red[2] + red[3]);
  __syncthreads();
  float lse = lse_s;
  int kblk = i >> 5, quad = (i >> 3) & 3, idx = i & 7;
#pragma unroll
  for (int q = 0; q < 4; ++q) {
    int j = q * 256 + tid;
    int pos = (((j >> 4) * 32 + kblk) * 64 + quad * 16 + (j & 15)) * 8 + idx;
    texp_frag[pos] = f2bf(__expf(x[q] - lse));
  }
}

// ---------------- fused: gemm0 (512) + gemm1 (640) + shead (1) ----------------
__global__ __launch_bounds__(256) void g01s_kernel(
    const ushort* At, const ushort* Bt, const float* t_bo, float* tlogits,
    const ushort* Ae, const ushort* Be, const float* e_bo, float* esum,
    const float* h_s, const float* s_Wo, const float* s_bo, float* start_v)
{
  int p = blockIdx.x;
  if (p < 512) {
    gemm_body(At, Bt, 0, 1024, 1, t_bo, tlogits, nullptr, nullptr, p & 15, p >> 4);
  } else if (p < 1152) {
    int q = p - 512;
    gemm_body(Ae, Be, 1, 10000, 8, e_bo, nullptr, esum, nullptr, q & 15, q >> 4);
  } else {
    shead_body(h_s, s_Wo, s_bo, start_v);
  }
}

// ---------------- fused: trans (1024) + gemm2 (2048) ----------------
__global__ __launch_bounds__(256) void tg2_kernel(
    const float* tlogits, ushort* texp_frag,
    const ushort* Ae, const ushort* Be, const float* e_bo, float* emitg,
    float* esum, const int* text)
{
  int p = blockIdx.x;
  if (p < 1024) {
    trans_body(tlogits, texp_frag, p);
  } else {
    int q = p - 1024;
    gemm_body(Ae, Be, 2, 4096, 1, e_bo, emitg, esum, text, q & 15, q >> 4);
  }
}

// ---------------- persistent forward scan: 4 batch-groups x 16 col-blocks ----------------
// R11/R9 proven-best structure verbatim (601-608us floor): T in AGPRs via asm MFMA "a"
// operands (asm-volatile results can't be rematerialized -> loads happen once),
// exp/log exchange, full-set poll with s_sleep(1), 4 independent MFMA chains,
// 1 barrier/step. Exchange floor: 255 serial cross-workgroup rounds x ~1.9us L3
// visibility RTT - all mechanism levers (poll width/mask/pipeline, store flavor,
// backoff, fan-in topology, producer overlap) measured null or negative
// (R6/R7/R8/R10/R12/R14). The scan MUST run alone: R14 showed concurrent producer
// traffic inflates the exchange RTT ~50%.
__global__ __launch_bounds__(256, 1) void scan_kernel(
    const ushort* __restrict__ texp_frag,
    const float* __restrict__ emitg,
    const float* __restrict__ start_v,
    u64* __restrict__ abuf,            // [2 parity][4 group][2048]
    float* __restrict__ out)
{
  __shared__ __align__(16) char Asb[2][4 * 2080];  // 16.3 KB: [parity][row*2080 + 2*col]
  __shared__ float redw[4][4], reds[4][4];

  int tid = threadIdx.x, lane = tid & 63, wave = tid >> 6;
  int r16 = lane & 15, quad = lane >> 4;
  int p = blockIdx.x, bg = p & 3, cb = p >> 2;
  int b0 = bg * 4;                      // global batches b0..b0+3

  // one-time load of this wave's T tile; pin into AGPRs
  const short8* tg = (const short8*)texp_frag + (size_t)cb * 8192 + wave * 2048;
  short8 treg[32];
#pragma unroll
  for (int k = 0; k < 32; ++k) treg[k] = tg[k * 64 + lane];
#pragma unroll
  for (int k = 0; k < 32; ++k) asm volatile("" : "+a"(treg[k]));

  int colw = cb * 64 + wave * 16 + r16;           // this lane's output col
  int abase = (r16 & 3) * 2080 + quad * 16;       // A-frag byte offset (garbage rows ok)

  float m_r[4], Bs[4];
  // ---- seed: A(0) = exp(alpha0 - alpha0[col0]), offset = alpha0[col0] ----
#pragma unroll
  for (int i = 0; i < 4; ++i) {
    m_r[i] = start_v[0] + emitg[(size_t)(b0 + i) * 1024];
    Bs[i] = m_r[i];
  }
  {
    int c0 = 2 * tid, c2 = 2 * tid + 512;
    char* ab = Asb[1];
#pragma unroll
    for (int r = 0; r < 4; ++r) {
      const float* eb = emitg + (size_t)(b0 + r) * 1024;
      float v0 = start_v[c0] + eb[c0],     v1 = start_v[c0 + 1] + eb[c0 + 1];
      float v2 = start_v[c2] + eb[c2],     v3 = start_v[c2 + 1] + eb[c2 + 1];
      *(u32*)(ab + r * 2080 + 4 * tid)        = pk2(v0 - m_r[r], v1 - m_r[r]);
      *(u32*)(ab + r * 2080 + 1024 + 4 * tid) = pk2(v2 - m_r[r], v3 - m_r[r]);
    }
  }
  __syncthreads();   // t=1 pack ready

  for (int t = 1; t < 256; ++t) {
    // emission prefetch (off critical chain; consumed after K-loop)
    float e0 = 0.f, e1 = 0.f, e2 = 0.f, e3 = 0.f;
    if (quad == 0) {
      const float* ep = emitg + (size_t)(t * 16 + b0) * 1024 + colw;
      e0 = ep[0]; e1 = ep[1024]; e2 = ep[2048]; e3 = ep[3072];
    }

    // K-loop: B from AGPRs (asm), A broadcast-read from LDS; 4 independent chains
    const char* ab = Asb[t & 1];
    f32x4 a0, a1, a2, a3;
    {
      short8 f0 = *(const short8*)(ab + abase);
      short8 f1 = *(const short8*)(ab + abase + 64);
      short8 f2 = *(const short8*)(ab + abase + 128);
      short8 f3 = *(const short8*)(ab + abase + 192);
      asm volatile("v_mfma_f32_16x16x32_bf16 %0, %1, %2, 0" : "=v"(a0) : "v"(f0), "a"(treg[0]));
      asm volatile("v_mfma_f32_16x16x32_bf16 %0, %1, %2, 0" : "=v"(a1) : "v"(f1), "a"(treg[1]));
      asm volatile("v_mfma_f32_16x16x32_bf16 %0, %1, %2, 0" : "=v"(a2) : "v"(f2), "a"(treg[2]));
      asm volatile("v_mfma_f32_16x16x32_bf16 %0, %1, %2, 0" : "=v"(a3) : "v"(f3), "a"(treg[3]));
    }
#pragma unroll
    for (int kb = 4; kb < 32; kb += 4) {
      short8 f0 = *(const short8*)(ab + abase + kb * 64);
      short8 f1 = *(const short8*)(ab + abase + kb * 64 + 64);
      short8 f2 = *(const short8*)(ab + abase + kb * 64 + 128);
      short8 f3 = *(const short8*)(ab + abase + kb * 64 + 192);
      asm volatile("v_mfma_f32_16x16x32_bf16 %0, %1, %2, %0" : "+v"(a0) : "v"(f0), "a"(treg[kb + 0]));
      asm volatile("v_mfma_f32_16x16x32_bf16 %0, %1, %2, %0" : "+v"(a1) : "v"(f1), "a"(treg[kb + 1]));
      asm volatile("v_mfma_f32_16x16x32_bf16 %0, %1, %2, %0" : "+v"(a2) : "v"(f2), "a"(treg[kb + 2]));
      asm volatile("v_mfma_f32_16x16x32_bf16 %0, %1, %2, %0" : "+v"(a3) : "v"(f3), "a"(treg[kb + 3]));
    }
    asm volatile("s_nop 7\n\ts_nop 7\n\ts_nop 1"
                 : "+v"(a0), "+v"(a1), "+v"(a2), "+v"(a3));
    f32x4 acc = (a0 + a1) + (a2 + a3);

    // epilogue: quad0 lanes hold batches b0..b0+3 (rows 0-3) for col colw
    if (quad == 0) {
      float d0 = __logf(acc[0]) + e0;
      float d1 = __logf(acc[1]) + e1;
      float d2 = __logf(acc[2]) + e2;
      float d3 = __logf(acc[3]) + e3;
      u64 tag = ((u64)(u32)t) << 32;
      u64* ob = abuf + (t & 1) * 8192 + bg * 2048 + colw;
      AS(ob,        tag | (u64)((u32)f2bf(d0) | ((u32)f2bf(d1) << 16)));
      AS(ob + 1024, tag | (u64)((u32)f2bf(d2) | ((u32)f2bf(d3) << 16)));
    }

    if (t < 255) {
      // poll tag t: 8 data words (4 cols x 2 batch-pairs) + 2 normalizer (col-0) words
      u64 x0, x1, x2, x3, x4, x5, x6, x7, n0, n1;
      {
        const u64* buf = abuf + (t & 1) * 8192 + bg * 2048;
        int oa = 2 * tid, oc = 2 * tid + 512;
        u32 want = (u32)t;
        bool first = true;
        for (;;) {
          if (!first) __builtin_amdgcn_s_sleep(1);
          first = false;
          x0 = AL(buf + oa);        x1 = AL(buf + oa + 1);
          x2 = AL(buf + oc);        x3 = AL(buf + oc + 1);
          x4 = AL(buf + 1024 + oa); x5 = AL(buf + 1024 + oa + 1);
          x6 = AL(buf + 1024 + oc); x7 = AL(buf + 1024 + oc + 1);
          n0 = AL(buf);             n1 = AL(buf + 1024);
          u32 bad = ((u32)(x0 >> 32) ^ want) | ((u32)(x1 >> 32) ^ want) |
                    ((u32)(x2 >> 32) ^ want) | ((u32)(x3 >> 32) ^ want) |
                    ((u32)(x4 >> 32) ^ want) | ((u32)(x5 >> 32) ^ want) |
                    ((u32)(x6 >> 32) ^ want) | ((u32)(x7 >> 32) ^ want) |
                    ((u32)(n0 >> 32) ^ want) | ((u32)(n1 >> 32) ^ want);
          if (bad == 0) break;
        }
      }
      m_r[0] = bflo2f((u32)n0); m_r[1] = bfhi2f((u32)n0);
      m_r[2] = bflo2f((u32)n1); m_r[3] = bfhi2f((u32)n1);
      Bs[0] += m_r[0]; Bs[1] += m_r[1]; Bs[2] += m_r[2]; Bs[3] += m_r[3];

      // pack A(t+1): row r <- batch b0+r; lo/hi select within batch-pair words
      char* aw = Asb[(t + 1) & 1];
      u32 l0 = (u32)x0, l1 = (u32)x1, l2 = (u32)x2, l3 = (u32)x3;
      u32 l4 = (u32)x4, l5 = (u32)x5, l6 = (u32)x6, l7 = (u32)x7;
      *(u32*)(aw + 4 * tid)                = pk2(bflo2f(l0) - m_r[0], bflo2f(l1) - m_r[0]);
      *(u32*)(aw + 1024 + 4 * tid)         = pk2(bflo2f(l2) - m_r[0], bflo2f(l3) - m_r[0]);
      *(u32*)(aw + 2080 + 4 * tid)         = pk2(bfhi2f(l0) - m_r[1], bfhi2f(l1) - m_r[1]);
      *(u32*)(aw + 2080 + 1024 + 4 * tid)  = pk2(bfhi2f(l2) - m_r[1], bfhi2f(l3) - m_r[1]);
      *(u32*)(aw + 4160 + 4 * tid)         = pk2(bflo2f(l4) - m_r[2], bflo2f(l5) - m_r[2]);
      *(u32*)(aw + 4160 + 1024 + 4 * tid)  = pk2(bflo2f(l6) - m_r[2], bflo2f(l7) - m_r[2]);
      *(u32*)(aw + 6240 + 4 * tid)         = pk2(bfhi2f(l4) - m_r[3], bfhi2f(l5) - m_r[3]);
      *(u32*)(aw + 6240 + 1024 + 4 * tid)  = pk2(bfhi2f(l6) - m_r[3], bfhi2f(l7) - m_r[3]);
      __syncthreads();   // A(t+1) ready (only barrier per step)
    }
  }

  // ---- group leader (cb==0): reduce final delta + Bs -> atomicAdd(out) ----
  if (cb == 0) {
    const u64* fb = abuf + 8192 + bg * 2048;   // parity of t=255
    int oa = 2 * tid, oc = 2 * tid + 512;
    u64 x0, x1, x2, x3, x4, x5, x6, x7;
    {
      bool first = true;
      for (;;) {
        if (!first) __builtin_amdgcn_s_sleep(1);
        first = false;
        x0 = AL(fb + oa);        x1 = AL(fb + oa + 1);
        x2 = AL(fb + oc);        x3 = AL(fb + oc + 1);
        x4 = AL(fb + 1024 + oa); x5 = AL(fb + 1024 + oa + 1);
        x6 = AL(fb + 1024 + oc); x7 = AL(fb + 1024 + oc + 1);
        u32 bad = ((u32)(x0 >> 32) ^ 255u) | ((u32)(x1 >> 32) ^ 255u) |
                  ((u32)(x2 >> 32) ^ 255u) | ((u32)(x3 >> 32) ^ 255u) |
                  ((u32)(x4 >> 32) ^ 255u) | ((u32)(x5 >> 32) ^ 255u) |
                  ((u32)(x6 >> 32) ^ 255u) | ((u32)(x7 >> 32) ^ 255u);
        if (bad == 0) break;
      }
    }
    float bv[4][4];
    bv[0][0] = bflo2f((u32)x0); bv[0][1] = bflo2f((u32)x1); bv[0][2] = bflo2f((u32)x2); bv[0][3] = bflo2f((u32)x3);
    bv[1][0] = bfhi2f((u32)x0); bv[1][1] = bfhi2f((u32)x1); bv[1][2] = bfhi2f((u32)x2); bv[1][3] = bfhi2f((u32)x3);
    bv[2][0] = bflo2f((u32)x4); bv[2][1] = bflo2f((u32)x5); bv[2][2] = bflo2f((u32)x6); bv[2][3] = bflo2f((u32)x7);
    bv[3][0] = bfhi2f((u32)x4); bv[3][1] = bfhi2f((u32)x5); bv[3][2] = bfhi2f((u32)x6); bv[3][3] = bfhi2f((u32)x7);
    float M[4], S[4];
#pragma unroll
    for (int i = 0; i < 4; ++i)
      M[i] = fmaxf(fmaxf(bv[i][0], bv[i][1]), fmaxf(bv[i][2], bv[i][3]));
    for (int off = 1; off < 64; off <<= 1) {
#pragma unroll
      for (int i = 0; i < 4; ++i) M[i] = fmaxf(M[i], __shfl_xor(M[i], off));
    }
    if (lane == 0) { redw[wave][0]=M[0]; redw[wave][1]=M[1]; redw[wave][2]=M[2]; redw[wave][3]=M[3]; }
    __syncthreads();
#pragma unroll
    for (int i = 0; i < 4; ++i)
      M[i] = fmaxf(fmaxf(redw[0][i], redw[1][i]), fmaxf(redw[2][i], redw[3][i]));
#pragma unroll
    for (int i = 0; i < 4; ++i)
      S[i] = __expf(bv[i][0] - M[i]) + __expf(bv[i][1] - M[i]) +
             __expf(bv[i][2] - M[i]) + __expf(bv[i][3] - M[i]);
    for (int off = 1; off < 64; off <<= 1) {
#pragma unroll
      for (int i = 0; i < 4; ++i) S[i] += __shfl_xor(S[i], off);
    }
    if (lane == 0) { reds[wave][0]=S[0]; reds[wave][1]=S[1]; reds[wave][2]=S[2]; reds[wave][3]=S[3]; }
    __syncthreads();
    if (tid == 0) {
      float tot = 0.f;
#pragma unroll
      for (int i = 0; i < 4; ++i) {
        float Sg = reds[0][i] + reds[1][i] + reds[2][i] + reds[3][i];
        tot += Bs[i] + M[i] + logf(Sg);
      }
      atomicAdd(out, tot);
    }
  }
}

extern "C" void kernel_launch(void* const* d_in, const int* in_sizes, int n_in,
                              void* d_out, int out_size, void* d_ws, size_t ws_size,
                              hipStream_t stream)
{
  (void)in_sizes; (void)n_in; (void)out_size; (void)ws_size;
  const float* start_emb = (const float*)d_in[0];
  const float* state_emb = (const float*)d_in[1];
  const float* pre_emb   = (const float*)d_in[2];
  const float* s_W1 = (const float*)d_in[3];  const float* s_b1 = (const float*)d_in[4];
  const float* s_W2 = (const float*)d_in[5];  const float* s_b2 = (const float*)d_in[6];
  const float* s_g  = (const float*)d_in[7];  const float* s_be = (const float*)d_in[8];
  const float* s_Wo = (const float*)d_in[9];  const float* s_bo = (const float*)d_in[10];
  const float* t_W1 = (const float*)d_in[11]; const float* t_b1 = (const float*)d_in[12];
  const float* t_W2 = (const float*)d_in[13]; const float* t_b2 = (const float*)d_in[14];
  const float* t_g  = (const float*)d_in[15]; const float* t_be = (const float*)d_in[16];
  const float* t_Wo = (const float*)d_in[17]; const float* t_bo = (const float*)d_in[18];
  const float* e_W1 = (const float*)d_in[19]; const float* e_b1 = (const float*)d_in[20];
  const float* e_W2 = (const float*)d_in[21]; const float* e_b2 = (const float*)d_in[22];
  const float* e_g  = (const float*)d_in[23]; const float* e_be = (const float*)d_in[24];
  const float* e_Wo = (const float*)d_in[25]; const float* e_bo = (const float*)d_in[26];
  const int*   text = (const int*)d_in[27];
  float* out = (float*)d_out;

  char* ws = (char*)d_ws;
  size_t off = 0;
  auto alloc = [&](size_t bytes) -> char* {
    char* p = ws + off;
    off = (off + bytes + 255) & ~(size_t)255;
    return p;
  };
  float* esum       = (float*)alloc(1024 * 4);     // @0 (memset)
  u64*   abuf       = (u64*)alloc(2 * 8192 * 8);   // 128KB tagged exchange (memset)
  float* start_v    = (float*)alloc(1024 * 4);
  float* h_s        = (float*)alloc(1024 * 256 * 4);
  ushort* h_t_bf    = (ushort*)alloc(1024 * 256 * 2);
  ushort* h_e_bf    = (ushort*)alloc(1024 * 256 * 2);
  ushort* tWo_bf    = (ushort*)alloc(1024 * 256 * 2);
  ushort* eWo_bf    = (ushort*)alloc(10000 * 256 * 2);
  float* tlogits    = (float*)alloc(1024 * 1024 * 4);
  ushort* texp_frag = (ushort*)alloc(1024 * 1024 * 2);
  float* emitg      = (float*)alloc(4096 * 1024 * 4);

  hipMemsetAsync(ws, 0, 4096 + 2 * 8192 * 8, stream);  // esum + abuf (kill stale tags)
  hipMemsetAsync(d_out, 0, 4, stream);                 // leaders atomicAdd into out

  mlp3_kernel<<<dim3(64, 4), 256, 0, stream>>>(
      start_emb, s_W1, s_b1, s_W2, s_b2, s_g, s_be, h_s, nullptr,
      state_emb, t_W1, t_b1, t_W2, t_b2, t_g, t_be, nullptr, h_t_bf,
      pre_emb,  e_W1, e_b1, e_W2, e_b2, e_g, e_be, nullptr, h_e_bf,
      t_Wo, tWo_bf, 1024 * 256, e_Wo, eWo_bf, 10000 * 256);

  g01s_kernel<<<1153, 256, 0, stream>>>(
      h_t_bf, tWo_bf, t_bo, tlogits,
      h_e_bf, eWo_bf, e_bo, esum,
      h_s, s_Wo, s_bo, start_v);

  tg2_kernel<<<3072, 256, 0, stream>>>(
      tlogits, texp_frag,
      h_e_bf, eWo_bf, e_bo, emitg,
      esum, text);

  scan_kernel<<<64, 256, 0, stream>>>(texp_frag, emitg, start_v, abuf, out);
}